// Round 7
// baseline (818.097 us; speedup 1.0000x reference)
//
#include <hip/hip_runtime.h>
#include <hip/hip_fp16.h>
#include <math.h>

#define N_NODES 50000
#define N_EDGES 800000
#define D_FEAT  64
#define BSHIFT  6
#define NBKT    782               // ceil(50000/64)
#define NB      64                // coarse blocks
#define CHUNK   12500             // 64*12500 = 800000 exactly
#define PSHIFT  20
#define SRC_MASK ((1 << PSHIFT) - 1)   // src < 50000 < 2^20

// ---------- workspace layout (ints) ----------
#define WS_FLAG    0
#define WS_TOT     64                         // per-bucket totals [NBKT]
#define WS_COFF    (WS_TOT + NBKT)            // bucket base offsets [NBKT+1]
#define WS_BH      (WS_COFF + NBKT + 1)       // per-block bucket counts [NB*NBKT]
#define WS_PAIR    (WS_BH + NB * NBKT)        // packed (src|dstlow<<20) [N_EDGES]
#define WS_PACKED  (WS_PAIR + N_EDGES)        // __half2[N_NODES*D_FEAT]
#define WS_INTS    (WS_PACKED + N_NODES * D_FEAT)

__device__ inline void detect_idx_layout(const int* idx, int* flag) {
    // indices < 50000: if stored as int64 LE, every odd 32-bit word is 0.
    int allzero = 1;
    #pragma unroll
    for (int i = 1; i < 129; i += 2) {
        if (idx[i] != 0) allzero = 0;
    }
    *flag = allzero;
}

// K0: detect layout, cast+interleave features to fp16
__global__ __launch_bounds__(256) void init_cast(int* __restrict__ W,
                                                 const int* __restrict__ idx,
                                                 const float* __restrict__ xs,
                                                 const float* __restrict__ xp) {
    int tid = blockIdx.x * blockDim.x + threadIdx.x;
    int stride = gridDim.x * blockDim.x;
    __half2* packed = (__half2*)(W + WS_PACKED);
    const int total = N_NODES * D_FEAT;
    for (int i = tid; i < total; i += stride)
        packed[i] = __floats2half2_rn(xs[i], xp[i]);
    if (tid == 0) detect_idx_layout(idx, W + WS_FLAG);
}

// K1: per-block LDS histogram over coarse buckets -> bh[block][bucket]
__global__ __launch_bounds__(256) void block_hist(const int* __restrict__ idx,
                                                  int* __restrict__ W) {
    __shared__ int h[NBKT];
    for (int i = threadIdx.x; i < NBKT; i += 256) h[i] = 0;
    __syncthreads();
    const int flg = W[WS_FLAG];
    const int base = blockIdx.x * CHUNK;
    for (int e = base + threadIdx.x; e < base + CHUNK; e += 256) {
        int dst = flg ? idx[2 * (N_EDGES + e)] : idx[N_EDGES + e];
        atomicAdd(&h[dst >> BSHIFT], 1);
    }
    __syncthreads();
    for (int i = threadIdx.x; i < NBKT; i += 256)
        W[WS_BH + blockIdx.x * NBKT + i] = h[i];
}

// K2a: per-bucket exclusive scan over NB block counts -> within-offsets + totals
__global__ __launch_bounds__(64) void bucket_scan(int* __restrict__ W) {
    int j = blockIdx.x;           // bucket
    int l = threadIdx.x;          // block index (NB=64 lanes)
    int c = W[WS_BH + l * NBKT + j];
    int incl = c;
    #pragma unroll
    for (int off = 1; off < 64; off <<= 1) {
        int u = __shfl_up(incl, off, 64);
        if (l >= off) incl += u;
    }
    W[WS_BH + l * NBKT + j] = incl - c;   // exclusive within-bucket offset
    if (l == 63) W[WS_TOT + j] = incl;
}

// K2b: single-block scan of bucket totals -> COFF
__global__ __launch_bounds__(1024) void base_scan(int* __restrict__ W) {
    __shared__ int part[1024];
    int t = threadIdx.x;
    int v = (t < NBKT) ? W[WS_TOT + t] : 0;
    part[t] = v;
    __syncthreads();
    for (int off = 1; off < 1024; off <<= 1) {
        int u = (t >= off) ? part[t - off] : 0;
        __syncthreads();
        part[t] += u;
        __syncthreads();
    }
    if (t < NBKT) W[WS_COFF + t] = part[t] - v;
    if (t == 0) W[WS_COFF + NBKT] = N_EDGES;
}

// K3: deterministic coarse scatter — no global atomics
__global__ __launch_bounds__(256) void coarse_scatter(const int* __restrict__ idx,
                                                      int* __restrict__ W) {
    __shared__ int cur[NBKT];
    for (int i = threadIdx.x; i < NBKT; i += 256)
        cur[i] = W[WS_COFF + i] + W[WS_BH + blockIdx.x * NBKT + i];
    __syncthreads();
    const int flg = W[WS_FLAG];
    const int base = blockIdx.x * CHUNK;
    for (int e = base + threadIdx.x; e < base + CHUNK; e += 256) {
        int src, dst;
        if (flg) { src = idx[2 * e]; dst = idx[2 * (N_EDGES + e)]; }
        else     { src = idx[e];     dst = idx[N_EDGES + e]; }
        int pos = atomicAdd(&cur[dst >> BSHIFT], 1);
        W[WS_PAIR + pos] = src | ((dst & 63) << PSHIFT);
    }
}

// K4: fused fine-sort + gather. One block per bucket; LDS accumulators.
// sum in fp32; product accumulated in log2-space (x_prod is uniform[0,1) >= 0).
__global__ __launch_bounds__(256) void bucket_gather(const int* __restrict__ W,
                                                     float* __restrict__ out) {
    __shared__ float acc_s[64][64];
    __shared__ float acc_p[64][64];
    int j = blockIdx.x;
    int t = threadIdx.x;
    int w = t >> 6;            // wave id (4 waves)
    int lane = t & 63;

    for (int i = t; i < 64 * 64; i += 256) {
        ((float*)acc_s)[i] = 0.f;
        ((float*)acc_p)[i] = 0.f;
    }
    __syncthreads();

    int beg = W[WS_COFF + j];
    int cnt = W[WS_COFF + j + 1] - beg;
    const int* pair = W + WS_PAIR;
    const __half2* packed = (const __half2*)(W + WS_PACKED);

    // each wave takes 64-edge tiles round-robin
    for (int tile = w * 64; tile < cnt; tile += 4 * 64) {
        int nload = min(64, cnt - tile);
        int val = (lane < nload) ? pair[beg + tile + lane] : 0;
        #pragma unroll 4
        for (int k = 0; k < nload; ++k) {
            int v = __shfl(val, k, 64);
            int srcn = v & SRC_MASK;
            int nl = ((unsigned)v) >> PSHIFT;
            float2 f = __half22float2(packed[srcn * D_FEAT + lane]);
            atomicAdd(&acc_s[nl][lane], f.x);
            atomicAdd(&acc_p[nl][lane], __log2f(f.y));
        }
    }
    __syncthreads();

    for (int nl = w; nl < 64; nl += 4) {
        int node = (j << BSHIFT) + nl;
        if (node < N_NODES) {
            out[(long)node * D_FEAT + lane] = acc_s[nl][lane];
            out[(long)N_NODES * D_FEAT + (long)node * D_FEAT + lane] =
                exp2f(acc_p[nl][lane]);
        }
    }
}

// ---------------- fallback (atomic) path, used only if ws is too small ----------------
__device__ inline void atomicMulF32(float* addr, float val) {
    unsigned int* ua = (unsigned int*)addr;
    unsigned int old = __hip_atomic_load(ua, __ATOMIC_RELAXED, __HIP_MEMORY_SCOPE_AGENT);
    while (true) {
        unsigned int assumed = old;
        unsigned int desired = __float_as_uint(__uint_as_float(assumed) * val);
        old = atomicCAS(ua, assumed, desired);
        if (old == assumed) break;
    }
}

__global__ void fb_init(float* __restrict__ out, int* __restrict__ flag,
                        const int* __restrict__ idx) {
    const int n4 = (N_NODES * D_FEAT) / 4;
    int tid = blockIdx.x * blockDim.x + threadIdx.x;
    int stride = gridDim.x * blockDim.x;
    float4* o = (float4*)out;
    const float4 z = make_float4(0.f, 0.f, 0.f, 0.f);
    const float4 one = make_float4(1.f, 1.f, 1.f, 1.f);
    for (int i = tid; i < n4; i += stride) { o[i] = z; o[n4 + i] = one; }
    if (blockIdx.x == 0 && threadIdx.x == 0) detect_idx_layout(idx, flag);
}

__global__ void fb_scatter(const float* __restrict__ xs, const float* __restrict__ xp,
                           const int* __restrict__ idx, float* __restrict__ out,
                           const int* __restrict__ flag) {
    long tid = (long)blockIdx.x * blockDim.x + threadIdx.x;
    const long total = (long)N_EDGES * (D_FEAT / 4);
    if (tid >= total) return;
    int e = (int)(tid >> 4);
    int c = (int)(tid & 15);
    int src, dst;
    if (*flag) { src = idx[2 * e]; dst = idx[2 * (N_EDGES + e)]; }
    else       { src = idx[e];     dst = idx[N_EDGES + e]; }
    const float4 s = ((const float4*)(xs + (long)src * D_FEAT))[c];
    const float4 p = ((const float4*)(xp + (long)src * D_FEAT))[c];
    float* os = out + (long)dst * D_FEAT + c * 4;
    float* op = out + (long)N_NODES * D_FEAT + (long)dst * D_FEAT + c * 4;
    atomicAdd(os + 0, s.x); atomicAdd(os + 1, s.y);
    atomicAdd(os + 2, s.z); atomicAdd(os + 3, s.w);
    atomicMulF32(op + 0, p.x); atomicMulF32(op + 1, p.y);
    atomicMulF32(op + 2, p.z); atomicMulF32(op + 3, p.w);
}

extern "C" void kernel_launch(void* const* d_in, const int* in_sizes, int n_in,
                              void* d_out, int out_size, void* d_ws, size_t ws_size,
                              hipStream_t stream) {
    const float* x_sum  = (const float*)d_in[0];
    const float* x_prod = (const float*)d_in[1];
    const int*   eidx   = (const int*)d_in[2];
    float* out = (float*)d_out;
    int* W = (int*)d_ws;

    if (ws_size < (size_t)WS_INTS * sizeof(int)) {
        fb_init<<<1024, 256, 0, stream>>>(out, W, eidx);
        const long total = (long)N_EDGES * (D_FEAT / 4);
        int grid = (int)((total + 255) / 256);
        fb_scatter<<<grid, 256, 0, stream>>>(x_sum, x_prod, eidx, out, W);
        return;
    }

    init_cast<<<1024, 256, 0, stream>>>(W, eidx, x_sum, x_prod);
    block_hist<<<NB, 256, 0, stream>>>(eidx, W);
    bucket_scan<<<NBKT, 64, 0, stream>>>(W);
    base_scan<<<1, 1024, 0, stream>>>(W);
    coarse_scatter<<<NB, 256, 0, stream>>>(eidx, W);
    bucket_gather<<<NBKT, 256, 0, stream>>>(W, out);
}

// Round 8
// 171.338 us; speedup vs baseline: 4.7747x; 4.7747x over previous
//
#include <hip/hip_runtime.h>
#include <hip/hip_fp16.h>

#define N_NODES 50000
#define N_EDGES 800000
#define D_FEAT  64
#define BSHIFT  6
#define NBKT    782               // ceil(50000/64)
#define NB      64                // coarse blocks
#define CHUNK   12500             // 64*12500 = 800000 exactly
#define PSHIFT  20
#define SRC_MASK ((1 << PSHIFT) - 1)   // src < 50000 < 2^20

// ---------- workspace layout (ints) ----------
#define WS_FLAG    0
#define WS_TOT     64                         // per-bucket totals [NBKT]
#define WS_COFF    (WS_TOT + NBKT)            // bucket base offsets [NBKT+1]
#define WS_BH      (WS_COFF + NBKT + 1)       // per-block bucket counts [NB*NBKT]
#define WS_OFFS    (WS_BH + NB * NBKT)        // per-node offsets [N_NODES+1]
#define WS_PAIR    (WS_OFFS + N_NODES + 1)    // packed (src|dstlow<<20) [N_EDGES]
#define WS_SSRC    (WS_PAIR + N_EDGES)        // dst-sorted src [N_EDGES]
#define WS_PACKED  (WS_SSRC + N_EDGES)        // __half2[N_NODES*D_FEAT]
#define WS_INTS    (WS_PACKED + N_NODES * D_FEAT)

__device__ inline void detect_idx_layout(const int* idx, int* flag) {
    // indices < 50000: if stored as int64 LE, every odd 32-bit word is 0.
    int allzero = 1;
    #pragma unroll
    for (int i = 1; i < 129; i += 2) {
        if (idx[i] != 0) allzero = 0;
    }
    *flag = allzero;
}

// K0: detect layout, cast+interleave features to fp16, set offs[N]
__global__ __launch_bounds__(256) void init_cast(int* __restrict__ W,
                                                 const int* __restrict__ idx,
                                                 const float* __restrict__ xs,
                                                 const float* __restrict__ xp) {
    int tid = blockIdx.x * blockDim.x + threadIdx.x;
    int stride = gridDim.x * blockDim.x;
    __half2* packed = (__half2*)(W + WS_PACKED);
    const int total = N_NODES * D_FEAT;
    for (int i = tid; i < total; i += stride)
        packed[i] = __floats2half2_rn(xs[i], xp[i]);
    if (tid == 0) {
        detect_idx_layout(idx, W + WS_FLAG);
        W[WS_OFFS + N_NODES] = N_EDGES;
    }
}

// K1: per-block LDS histogram over coarse buckets -> bh[block][bucket]
__global__ __launch_bounds__(256) void block_hist(const int* __restrict__ idx,
                                                  int* __restrict__ W) {
    __shared__ int h[NBKT];
    for (int i = threadIdx.x; i < NBKT; i += 256) h[i] = 0;
    __syncthreads();
    const int flg = W[WS_FLAG];
    const int base = blockIdx.x * CHUNK;
    for (int e = base + threadIdx.x; e < base + CHUNK; e += 256) {
        int dst = flg ? idx[2 * (N_EDGES + e)] : idx[N_EDGES + e];
        atomicAdd(&h[dst >> BSHIFT], 1);
    }
    __syncthreads();
    for (int i = threadIdx.x; i < NBKT; i += 256)
        W[WS_BH + blockIdx.x * NBKT + i] = h[i];
}

// K2a: per-bucket exclusive scan over NB block counts -> within-offsets + totals
__global__ __launch_bounds__(64) void bucket_scan(int* __restrict__ W) {
    int j = blockIdx.x;           // bucket
    int l = threadIdx.x;          // block index (NB=64 lanes)
    int c = W[WS_BH + l * NBKT + j];
    int incl = c;
    #pragma unroll
    for (int off = 1; off < 64; off <<= 1) {
        int u = __shfl_up(incl, off, 64);
        if (l >= off) incl += u;
    }
    W[WS_BH + l * NBKT + j] = incl - c;   // exclusive within-bucket offset
    if (l == 63) W[WS_TOT + j] = incl;
}

// K2b: single-block scan of bucket totals -> COFF
__global__ __launch_bounds__(1024) void base_scan(int* __restrict__ W) {
    __shared__ int part[1024];
    int t = threadIdx.x;
    int v = (t < NBKT) ? W[WS_TOT + t] : 0;
    part[t] = v;
    __syncthreads();
    for (int off = 1; off < 1024; off <<= 1) {
        int u = (t >= off) ? part[t - off] : 0;
        __syncthreads();
        part[t] += u;
        __syncthreads();
    }
    if (t < NBKT) W[WS_COFF + t] = part[t] - v;
    if (t == 0) W[WS_COFF + NBKT] = N_EDGES;
}

// K3: deterministic coarse scatter — LDS cursors, no global atomics
__global__ __launch_bounds__(256) void coarse_scatter(const int* __restrict__ idx,
                                                      int* __restrict__ W) {
    __shared__ int cur[NBKT];
    for (int i = threadIdx.x; i < NBKT; i += 256)
        cur[i] = W[WS_COFF + i] + W[WS_BH + blockIdx.x * NBKT + i];
    __syncthreads();
    const int flg = W[WS_FLAG];
    const int base = blockIdx.x * CHUNK;
    for (int e = base + threadIdx.x; e < base + CHUNK; e += 256) {
        int src, dst;
        if (flg) { src = idx[2 * e]; dst = idx[2 * (N_EDGES + e)]; }
        else     { src = idx[e];     dst = idx[N_EDGES + e]; }
        int pos = atomicAdd(&cur[dst >> BSHIFT], 1);
        W[WS_PAIR + pos] = src | ((dst & 63) << PSHIFT);
    }
}

// K4: per-bucket fine counting sort (LDS hist[64]) -> offs[node] + sorted ssrc
__global__ __launch_bounds__(256) void fine_sort(int* __restrict__ W) {
    __shared__ int h[64];
    int b = blockIdx.x;
    int t = threadIdx.x;
    int bbase = W[WS_COFF + b];
    int bend  = W[WS_COFF + b + 1];
    if (t < 64) h[t] = 0;
    __syncthreads();
    for (int e = bbase + t; e < bend; e += 256)
        atomicAdd(&h[(unsigned)W[WS_PAIR + e] >> PSHIFT], 1);
    __syncthreads();
    if (t < 64) {
        int c = h[t];
        int incl = c;
        #pragma unroll
        for (int off = 1; off < 64; off <<= 1) {
            int u = __shfl_up(incl, off, 64);
            if (t >= off) incl += u;
        }
        int excl = incl - c;
        int node = (b << BSHIFT) + t;
        if (node < N_NODES) W[WS_OFFS + node] = bbase + excl;
        h[t] = excl;   // becomes the local cursor
    }
    __syncthreads();
    for (int e = bbase + t; e < bend; e += 256) {
        int v = W[WS_PAIR + e];
        int p = atomicAdd(&h[(unsigned)v >> PSHIFT], 1);
        W[WS_SSRC + bbase + p] = v & SRC_MASK;
    }
}

// K5: one wave per node; lane = feature; fp16 interleaved gathers, fp32 accum
__global__ __launch_bounds__(256) void gather_reduce(const int* __restrict__ W,
                                                     float* __restrict__ out) {
    int wave = (int)((blockIdx.x * blockDim.x + threadIdx.x) >> 6);
    int lane = threadIdx.x & 63;
    if (wave >= N_NODES) return;
    int beg = W[WS_OFFS + wave];
    int end = W[WS_OFFS + wave + 1];
    const int* ssrc = W + WS_SSRC;
    const __half2* packed = (const __half2*)(W + WS_PACKED);

    float s0 = 0.f, s1 = 0.f, s2 = 0.f, s3 = 0.f;
    float p0 = 1.f, p1 = 1.f, p2 = 1.f, p3 = 1.f;
    int i = beg;
    for (; i + 3 < end; i += 4) {
        int a = ssrc[i], b = ssrc[i + 1], c = ssrc[i + 2], d = ssrc[i + 3];
        float2 fa = __half22float2(packed[a * D_FEAT + lane]);
        float2 fb = __half22float2(packed[b * D_FEAT + lane]);
        float2 fc = __half22float2(packed[c * D_FEAT + lane]);
        float2 fd = __half22float2(packed[d * D_FEAT + lane]);
        s0 += fa.x; s1 += fb.x; s2 += fc.x; s3 += fd.x;
        p0 *= fa.y; p1 *= fb.y; p2 *= fc.y; p3 *= fd.y;
    }
    for (; i < end; ++i) {
        float2 f = __half22float2(packed[ssrc[i] * D_FEAT + lane]);
        s0 += f.x;
        p0 *= f.y;
    }
    out[(long)wave * D_FEAT + lane] = (s0 + s1) + (s2 + s3);
    out[(long)N_NODES * D_FEAT + (long)wave * D_FEAT + lane] = (p0 * p1) * (p2 * p3);
}

// ---------------- fallback (atomic) path, used only if ws is too small ----------------
__device__ inline void atomicMulF32(float* addr, float val) {
    unsigned int* ua = (unsigned int*)addr;
    unsigned int old = __hip_atomic_load(ua, __ATOMIC_RELAXED, __HIP_MEMORY_SCOPE_AGENT);
    while (true) {
        unsigned int assumed = old;
        unsigned int desired = __float_as_uint(__uint_as_float(assumed) * val);
        old = atomicCAS(ua, assumed, desired);
        if (old == assumed) break;
    }
}

__global__ void fb_init(float* __restrict__ out, int* __restrict__ flag,
                        const int* __restrict__ idx) {
    const int n4 = (N_NODES * D_FEAT) / 4;
    int tid = blockIdx.x * blockDim.x + threadIdx.x;
    int stride = gridDim.x * blockDim.x;
    float4* o = (float4*)out;
    const float4 z = make_float4(0.f, 0.f, 0.f, 0.f);
    const float4 one = make_float4(1.f, 1.f, 1.f, 1.f);
    for (int i = tid; i < n4; i += stride) { o[i] = z; o[n4 + i] = one; }
    if (blockIdx.x == 0 && threadIdx.x == 0) detect_idx_layout(idx, flag);
}

__global__ void fb_scatter(const float* __restrict__ xs, const float* __restrict__ xp,
                           const int* __restrict__ idx, float* __restrict__ out,
                           const int* __restrict__ flag) {
    long tid = (long)blockIdx.x * blockDim.x + threadIdx.x;
    const long total = (long)N_EDGES * (D_FEAT / 4);
    if (tid >= total) return;
    int e = (int)(tid >> 4);
    int c = (int)(tid & 15);
    int src, dst;
    if (*flag) { src = idx[2 * e]; dst = idx[2 * (N_EDGES + e)]; }
    else       { src = idx[e];     dst = idx[N_EDGES + e]; }
    const float4 s = ((const float4*)(xs + (long)src * D_FEAT))[c];
    const float4 p = ((const float4*)(xp + (long)src * D_FEAT))[c];
    float* os = out + (long)dst * D_FEAT + c * 4;
    float* op = out + (long)N_NODES * D_FEAT + (long)dst * D_FEAT + c * 4;
    atomicAdd(os + 0, s.x); atomicAdd(os + 1, s.y);
    atomicAdd(os + 2, s.z); atomicAdd(os + 3, s.w);
    atomicMulF32(op + 0, p.x); atomicMulF32(op + 1, p.y);
    atomicMulF32(op + 2, p.z); atomicMulF32(op + 3, p.w);
}

extern "C" void kernel_launch(void* const* d_in, const int* in_sizes, int n_in,
                              void* d_out, int out_size, void* d_ws, size_t ws_size,
                              hipStream_t stream) {
    const float* x_sum  = (const float*)d_in[0];
    const float* x_prod = (const float*)d_in[1];
    const int*   eidx   = (const int*)d_in[2];
    float* out = (float*)d_out;
    int* W = (int*)d_ws;

    if (ws_size < (size_t)WS_INTS * sizeof(int)) {
        fb_init<<<1024, 256, 0, stream>>>(out, W, eidx);
        const long total = (long)N_EDGES * (D_FEAT / 4);
        int grid = (int)((total + 255) / 256);
        fb_scatter<<<grid, 256, 0, stream>>>(x_sum, x_prod, eidx, out, W);
        return;
    }

    init_cast<<<1024, 256, 0, stream>>>(W, eidx, x_sum, x_prod);
    block_hist<<<NB, 256, 0, stream>>>(eidx, W);
    bucket_scan<<<NBKT, 64, 0, stream>>>(W);
    base_scan<<<1, 1024, 0, stream>>>(W);
    coarse_scatter<<<NB, 256, 0, stream>>>(eidx, W);
    fine_sort<<<NBKT, 256, 0, stream>>>(W);
    gather_reduce<<<(N_NODES + 3) / 4, 256, 0, stream>>>(W, out);
}

// Round 9
// 148.161 us; speedup vs baseline: 5.5217x; 1.1564x over previous
//
#include <hip/hip_runtime.h>
#include <hip/hip_fp16.h>

#define N_NODES 50000
#define N_EDGES 800000
#define D_FEAT  64
#define BSHIFT  6
#define NBKT    782               // ceil(50000/64)
#define NB      256               // coarse blocks (1 per CU)
#define CHUNK   3125              // 256*3125 = 800000 exactly
#define PSHIFT  20
#define SRC_MASK ((1 << PSHIFT) - 1)   // src < 50000 < 2^20

// ---------- workspace layout (ints) ----------
#define WS_FLAG    0
#define WS_TOT     64                         // per-bucket totals [NBKT]
#define WS_COFF    (WS_TOT + NBKT)            // bucket base offsets [NBKT+1]
#define WS_BH      (WS_COFF + NBKT + 1)       // per-(bucket,block) counts [NBKT*NB]
#define WS_OFFS    (WS_BH + NBKT * NB)        // per-node offsets [N_NODES+1]
#define WS_PAIR    (WS_OFFS + N_NODES + 1)    // packed (src|dstlow<<20) [N_EDGES]
#define WS_SSRC    (WS_PAIR + N_EDGES)        // dst-sorted src [N_EDGES]
#define WS_PACKED  (WS_SSRC + N_EDGES)        // __half2[N_NODES*D_FEAT]
#define WS_INTS    (WS_PACKED + N_NODES * D_FEAT)

__device__ inline void detect_idx_layout(const int* idx, int* flag) {
    // indices < 50000: if stored as int64 LE, every odd 32-bit word is 0.
    int allzero = 1;
    #pragma unroll
    for (int i = 1; i < 129; i += 2) {
        if (idx[i] != 0) allzero = 0;
    }
    *flag = allzero;
}

// K0: detect layout, cast+interleave features to fp16, set offs[N]
__global__ __launch_bounds__(256) void init_cast(int* __restrict__ W,
                                                 const int* __restrict__ idx,
                                                 const float* __restrict__ xs,
                                                 const float* __restrict__ xp) {
    int tid = blockIdx.x * blockDim.x + threadIdx.x;
    int stride = gridDim.x * blockDim.x;
    __half2* packed = (__half2*)(W + WS_PACKED);
    const int total = N_NODES * D_FEAT;
    for (int i = tid; i < total; i += stride)
        packed[i] = __floats2half2_rn(xs[i], xp[i]);
    if (tid == 0) {
        detect_idx_layout(idx, W + WS_FLAG);
        W[WS_OFFS + N_NODES] = N_EDGES;
    }
}

// K1: per-block LDS histogram over coarse buckets -> BH[bucket][block]
__global__ __launch_bounds__(256) void block_hist(const int* __restrict__ idx,
                                                  int* __restrict__ W) {
    __shared__ int h[NBKT];
    for (int i = threadIdx.x; i < NBKT; i += 256) h[i] = 0;
    __syncthreads();
    const int flg = W[WS_FLAG];
    const int base = blockIdx.x * CHUNK;
    for (int e = base + threadIdx.x; e < base + CHUNK; e += 256) {
        int dst = flg ? idx[2 * (N_EDGES + e)] : idx[N_EDGES + e];
        atomicAdd(&h[dst >> BSHIFT], 1);
    }
    __syncthreads();
    for (int i = threadIdx.x; i < NBKT; i += 256)
        W[WS_BH + i * NB + blockIdx.x] = h[i];
}

// K2a: per-bucket exclusive scan over NB block counts (coalesced) -> excl + totals
__global__ __launch_bounds__(256) void bucket_scan(int* __restrict__ W) {
    __shared__ int part[NB];
    int j = blockIdx.x;           // bucket
    int t = threadIdx.x;          // block index
    int c = W[WS_BH + j * NB + t];
    part[t] = c;
    __syncthreads();
    for (int off = 1; off < NB; off <<= 1) {
        int u = (t >= off) ? part[t - off] : 0;
        __syncthreads();
        part[t] += u;
        __syncthreads();
    }
    W[WS_BH + j * NB + t] = part[t] - c;   // exclusive within-bucket offset
    if (t == NB - 1) W[WS_TOT + j] = part[t];
}

// K2b: single-block scan of bucket totals -> COFF
__global__ __launch_bounds__(1024) void base_scan(int* __restrict__ W) {
    __shared__ int part[1024];
    int t = threadIdx.x;
    int v = (t < NBKT) ? W[WS_TOT + t] : 0;
    part[t] = v;
    __syncthreads();
    for (int off = 1; off < 1024; off <<= 1) {
        int u = (t >= off) ? part[t - off] : 0;
        __syncthreads();
        part[t] += u;
        __syncthreads();
    }
    if (t < NBKT) W[WS_COFF + t] = part[t] - v;
    if (t == 0) W[WS_COFF + NBKT] = N_EDGES;
}

// K3: deterministic coarse scatter — LDS cursors, no global atomics
__global__ __launch_bounds__(256) void coarse_scatter(const int* __restrict__ idx,
                                                      int* __restrict__ W) {
    __shared__ int cur[NBKT];
    for (int i = threadIdx.x; i < NBKT; i += 256)
        cur[i] = W[WS_COFF + i] + W[WS_BH + i * NB + blockIdx.x];
    __syncthreads();
    const int flg = W[WS_FLAG];
    const int base = blockIdx.x * CHUNK;
    for (int e = base + threadIdx.x; e < base + CHUNK; e += 256) {
        int src, dst;
        if (flg) { src = idx[2 * e]; dst = idx[2 * (N_EDGES + e)]; }
        else     { src = idx[e];     dst = idx[N_EDGES + e]; }
        int pos = atomicAdd(&cur[dst >> BSHIFT], 1);
        W[WS_PAIR + pos] = src | ((dst & 63) << PSHIFT);
    }
}

// K4: per-bucket fine counting sort (LDS hist[64]) -> offs[node] + sorted ssrc
__global__ __launch_bounds__(256) void fine_sort(int* __restrict__ W) {
    __shared__ int h[64];
    int b = blockIdx.x;
    int t = threadIdx.x;
    int bbase = W[WS_COFF + b];
    int bend  = W[WS_COFF + b + 1];
    if (t < 64) h[t] = 0;
    __syncthreads();
    for (int e = bbase + t; e < bend; e += 256)
        atomicAdd(&h[(unsigned)W[WS_PAIR + e] >> PSHIFT], 1);
    __syncthreads();
    if (t < 64) {
        int c = h[t];
        int incl = c;
        #pragma unroll
        for (int off = 1; off < 64; off <<= 1) {
            int u = __shfl_up(incl, off, 64);
            if (t >= off) incl += u;
        }
        int excl = incl - c;
        int node = (b << BSHIFT) + t;
        if (node < N_NODES) W[WS_OFFS + node] = bbase + excl;
        h[t] = excl;   // becomes the local cursor
    }
    __syncthreads();
    for (int e = bbase + t; e < bend; e += 256) {
        int v = W[WS_PAIR + e];
        int p = atomicAdd(&h[(unsigned)v >> PSHIFT], 1);
        W[WS_SSRC + bbase + p] = v & SRC_MASK;
    }
}

// K5: one wave per node; lane = feature; fp16 interleaved gathers, fp32 accum.
// beg/end made SGPR-uniform so index loads scalarize; 8-deep gather pipeline.
__global__ __launch_bounds__(256) void gather_reduce(const int* __restrict__ W,
                                                     float* __restrict__ out) {
    int wave = (int)((blockIdx.x * blockDim.x + threadIdx.x) >> 6);
    int lane = threadIdx.x & 63;
    if (wave >= N_NODES) return;
    int beg = __builtin_amdgcn_readfirstlane(W[WS_OFFS + wave]);
    int end = __builtin_amdgcn_readfirstlane(W[WS_OFFS + wave + 1]);
    const int* ssrc = W + WS_SSRC;
    const __half2* packed = (const __half2*)(W + WS_PACKED);

    float s0 = 0.f, s1 = 0.f, s2 = 0.f, s3 = 0.f;
    float s4 = 0.f, s5 = 0.f, s6 = 0.f, s7 = 0.f;
    float p0 = 1.f, p1 = 1.f, p2 = 1.f, p3 = 1.f;
    float p4 = 1.f, p5 = 1.f, p6 = 1.f, p7 = 1.f;
    int i = beg;
    for (; i + 7 < end; i += 8) {
        int a0 = ssrc[i],     a1 = ssrc[i + 1], a2 = ssrc[i + 2], a3 = ssrc[i + 3];
        int a4 = ssrc[i + 4], a5 = ssrc[i + 5], a6 = ssrc[i + 6], a7 = ssrc[i + 7];
        float2 f0 = __half22float2(packed[a0 * D_FEAT + lane]);
        float2 f1 = __half22float2(packed[a1 * D_FEAT + lane]);
        float2 f2 = __half22float2(packed[a2 * D_FEAT + lane]);
        float2 f3 = __half22float2(packed[a3 * D_FEAT + lane]);
        float2 f4 = __half22float2(packed[a4 * D_FEAT + lane]);
        float2 f5 = __half22float2(packed[a5 * D_FEAT + lane]);
        float2 f6 = __half22float2(packed[a6 * D_FEAT + lane]);
        float2 f7 = __half22float2(packed[a7 * D_FEAT + lane]);
        s0 += f0.x; s1 += f1.x; s2 += f2.x; s3 += f3.x;
        s4 += f4.x; s5 += f5.x; s6 += f6.x; s7 += f7.x;
        p0 *= f0.y; p1 *= f1.y; p2 *= f2.y; p3 *= f3.y;
        p4 *= f4.y; p5 *= f5.y; p6 *= f6.y; p7 *= f7.y;
    }
    for (; i + 1 < end; i += 2) {
        int a0 = ssrc[i], a1 = ssrc[i + 1];
        float2 f0 = __half22float2(packed[a0 * D_FEAT + lane]);
        float2 f1 = __half22float2(packed[a1 * D_FEAT + lane]);
        s0 += f0.x; s1 += f1.x;
        p0 *= f0.y; p1 *= f1.y;
    }
    if (i < end) {
        float2 f = __half22float2(packed[ssrc[i] * D_FEAT + lane]);
        s0 += f.x;
        p0 *= f.y;
    }
    float ssum = ((s0 + s1) + (s2 + s3)) + ((s4 + s5) + (s6 + s7));
    float pprd = ((p0 * p1) * (p2 * p3)) * ((p4 * p5) * (p6 * p7));
    out[(long)wave * D_FEAT + lane] = ssum;
    out[(long)N_NODES * D_FEAT + (long)wave * D_FEAT + lane] = pprd;
}

// ---------------- fallback (atomic) path, used only if ws is too small ----------------
__device__ inline void atomicMulF32(float* addr, float val) {
    unsigned int* ua = (unsigned int*)addr;
    unsigned int old = __hip_atomic_load(ua, __ATOMIC_RELAXED, __HIP_MEMORY_SCOPE_AGENT);
    while (true) {
        unsigned int assumed = old;
        unsigned int desired = __float_as_uint(__uint_as_float(assumed) * val);
        old = atomicCAS(ua, assumed, desired);
        if (old == assumed) break;
    }
}

__global__ void fb_init(float* __restrict__ out, int* __restrict__ flag,
                        const int* __restrict__ idx) {
    const int n4 = (N_NODES * D_FEAT) / 4;
    int tid = blockIdx.x * blockDim.x + threadIdx.x;
    int stride = gridDim.x * blockDim.x;
    float4* o = (float4*)out;
    const float4 z = make_float4(0.f, 0.f, 0.f, 0.f);
    const float4 one = make_float4(1.f, 1.f, 1.f, 1.f);
    for (int i = tid; i < n4; i += stride) { o[i] = z; o[n4 + i] = one; }
    if (blockIdx.x == 0 && threadIdx.x == 0) detect_idx_layout(idx, flag);
}

__global__ void fb_scatter(const float* __restrict__ xs, const float* __restrict__ xp,
                           const int* __restrict__ idx, float* __restrict__ out,
                           const int* __restrict__ flag) {
    long tid = (long)blockIdx.x * blockDim.x + threadIdx.x;
    const long total = (long)N_EDGES * (D_FEAT / 4);
    if (tid >= total) return;
    int e = (int)(tid >> 4);
    int c = (int)(tid & 15);
    int src, dst;
    if (*flag) { src = idx[2 * e]; dst = idx[2 * (N_EDGES + e)]; }
    else       { src = idx[e];     dst = idx[N_EDGES + e]; }
    const float4 s = ((const float4*)(xs + (long)src * D_FEAT))[c];
    const float4 p = ((const float4*)(xp + (long)src * D_FEAT))[c];
    float* os = out + (long)dst * D_FEAT + c * 4;
    float* op = out + (long)N_NODES * D_FEAT + (long)dst * D_FEAT + c * 4;
    atomicAdd(os + 0, s.x); atomicAdd(os + 1, s.y);
    atomicAdd(os + 2, s.z); atomicAdd(os + 3, s.w);
    atomicMulF32(op + 0, p.x); atomicMulF32(op + 1, p.y);
    atomicMulF32(op + 2, p.z); atomicMulF32(op + 3, p.w);
}

extern "C" void kernel_launch(void* const* d_in, const int* in_sizes, int n_in,
                              void* d_out, int out_size, void* d_ws, size_t ws_size,
                              hipStream_t stream) {
    const float* x_sum  = (const float*)d_in[0];
    const float* x_prod = (const float*)d_in[1];
    const int*   eidx   = (const int*)d_in[2];
    float* out = (float*)d_out;
    int* W = (int*)d_ws;

    if (ws_size < (size_t)WS_INTS * sizeof(int)) {
        fb_init<<<1024, 256, 0, stream>>>(out, W, eidx);
        const long total = (long)N_EDGES * (D_FEAT / 4);
        int grid = (int)((total + 255) / 256);
        fb_scatter<<<grid, 256, 0, stream>>>(x_sum, x_prod, eidx, out, W);
        return;
    }

    init_cast<<<1024, 256, 0, stream>>>(W, eidx, x_sum, x_prod);
    block_hist<<<NB, 256, 0, stream>>>(eidx, W);
    bucket_scan<<<NBKT, 256, 0, stream>>>(W);
    base_scan<<<1, 1024, 0, stream>>>(W);
    coarse_scatter<<<NB, 256, 0, stream>>>(eidx, W);
    fine_sort<<<NBKT, 256, 0, stream>>>(W);
    gather_reduce<<<(N_NODES + 3) / 4, 256, 0, stream>>>(W, out);
}